// Round 11
// baseline (604.625 us; speedup 1.0000x reference)
//
#include <hip/hip_runtime.h>
#include <math.h>

#define I_DIM 384
#define C_DIM 128
#define H_NUM 4
#define HD_DIM 32
#define M_DIM (I_DIM*I_DIM)       // 147456
#define INF_F 1000000000.0f
#define EPS_F 1e-5f
#define QSCALE 0.17677669529663687f   // 1/sqrt(32)
#define LOG2E_F 1.4426950408889634f

typedef __attribute__((ext_vector_type(8))) short short8;
typedef __attribute__((ext_vector_type(4))) float f32x4;
union U4S8 { uint4 u; short8 s; };

__device__ __forceinline__ unsigned short f2bf(float f) {
    unsigned int u = __float_as_uint(f);
    u += 0x7fffu + ((u >> 16) & 1u);          // round-to-nearest-even
    return (unsigned short)(u >> 16);
}
__device__ __forceinline__ float bf2f(unsigned short h) {
    return __uint_as_float((unsigned int)h << 16);
}
__device__ __forceinline__ unsigned int pk2(float a, float b) {
    return (unsigned int)f2bf(a) | ((unsigned int)f2bf(b) << 16);
}
// HW packed f32->bf16 (RNE)
__device__ __forceinline__ unsigned int cvtpk(float lo, float hi) {
    unsigned int r;
    asm("v_cvt_pk_bf16_f32 %0, %1, %2" : "=v"(r) : "v"(lo), "v"(hi));
    return r;
}
// hi/lo split of one fp32 into a single uint: hi bf16 in low16, lo bf16 in hi16
__device__ __forceinline__ unsigned int hl32(float v) {
    const unsigned short h = f2bf(v);
    const unsigned short lo = f2bf(v - bf2f(h));
    return (unsigned int)h | ((unsigned int)lo << 16);
}

// ---------------------------------------------------------------------------
// Pre-formatted split weights, MFMA-B-fragment-linear:
//   wfmt_dev[mat(5)][s(2)][nt(8)][ks(4)][lane(64)] : uint4 (8 bf16, k-consec)
//   mats: 0=wq (pre-scaled by QSCALE*LOG2E), 1=wk, 2=wg, 3=wv, 4=wo
//   s=0: bf16(w); s=1: bf16(w - bf16(w))   (hi/lo split, ~fp32 when summed)
// ---------------------------------------------------------------------------
__device__ uint4 wfmt_dev[5*4096];     // 320 KB static device memory

__device__ __forceinline__ void load_lds16(const uint4* gp, void* lp) {
    __builtin_amdgcn_global_load_lds(
        (const __attribute__((address_space(1))) unsigned int*)gp,
        (__attribute__((address_space(3))) unsigned int*)lp,
        16, 0, 0);
}

__global__ __launch_bounds__(256) void wprep_kernel(
    const float* __restrict__ wq, const float* __restrict__ wk,
    const float* __restrict__ wg, const float* __restrict__ wv,
    const float* __restrict__ wo)
{
    const int tid  = blockIdx.x*256 + threadIdx.x;   // 80 blocks -> 320 tiles
    const int l    = tid & 63, tile = tid >> 6;
    const int ks   = tile & 3, nt = (tile >> 2) & 7;
    const int s    = (tile >> 5) & 1, m = tile >> 6;
    const float* W = (m==0)?wq:(m==1)?wk:(m==2)?wg:(m==3)?wv:wo;
    const float scale = (m==0) ? QSCALE*LOG2E_F : 1.f;  // fold exp2 conversion
    const int n  = nt*16 + (l & 15);
    const int kb = ks*32 + (l >> 4)*8;
    unsigned int hw[4];
    #pragma unroll
    for (int jp = 0; jp < 4; ++jp) {
        unsigned short hs[2];
        #pragma unroll
        for (int e = 0; e < 2; ++e) {
            float v = W[(size_t)(kb + jp*2 + e)*C_DIM + n] * scale;
            unsigned short h = f2bf(v);
            if (s) h = f2bf(v - bf2f(h));
            hs[e] = h;
        }
        hw[jp] = (unsigned int)hs[0] | ((unsigned int)hs[1] << 16);
    }
    wfmt_dev[(size_t)m*4096 + (size_t)((s*8 + nt)*4 + ks)*64 + l] =
        make_uint4(hw[0], hw[1], hw[2], hw[3]);
}

// ---------------------------------------------------------------------------
// Kernel 1: LayerNorm + z head + q/k/v/g projections via split-bf16 MFMA.
// (round-10 verified version, unchanged.)
// ---------------------------------------------------------------------------
__global__ __launch_bounds__(256, 3) void ln_proj_kernel(
    const float* __restrict__ x,
    const float* __restrict__ lnw, const float* __restrict__ lnb,
    const float* __restrict__ wz,  const float* __restrict__ bz,
    const float* __restrict__ bg,
    unsigned short* __restrict__ qo16, unsigned short* __restrict__ ko16,
    unsigned int* __restrict__ vto, float* __restrict__ go,
    float* __restrict__ zo)
{
    __shared__ __align__(16) unsigned int xs[4096];   // 16KB: hi, lo, then vts
    __shared__ __align__(16) uint4 wbuf4[2048];       // 2 x 16KB quarter dbuf
    unsigned int* vts = xs;

    const int t    = threadIdx.x;
    const int row0 = blockIdx.x * 64;
    const int w = t >> 6, l = t & 63, n16 = l & 15, quad = l >> 4;

    // ---- prefetch round 0 (wq, quarter 0) into buffer 0 ----
    #pragma unroll
    for (int it = 0; it < 4; ++it) {
        const int tl = w*4 + it;
        const int s = tl >> 3, ntl = (tl >> 2) & 1, ks = tl & 3;
        load_lds16(wfmt_dev + (size_t)((s*8 + ntl)*4 + ks)*64 + l,
                   (char*)wbuf4 + tl*1024);
    }

    // ---- Phase A: LayerNorm + z head; LN results kept in registers ----
    float4 xv[8];
    const int r = t >> 2, qt = t & 3, c0 = qt * 32;
    const int sw = (r & 7) << 2;
    {
        const float* xrow = x + (size_t)(row0 + r)*C_DIM + c0;
        float s = 0.f, ss = 0.f;
        #pragma unroll
        for (int i2 = 0; i2 < 8; i2++) {
            xv[i2] = ((const float4*)xrow)[i2];
            s  += xv[i2].x + xv[i2].y + xv[i2].z + xv[i2].w;
            ss += xv[i2].x*xv[i2].x + xv[i2].y*xv[i2].y
                + xv[i2].z*xv[i2].z + xv[i2].w*xv[i2].w;
        }
        s  += __shfl_xor(s, 1);  s  += __shfl_xor(s, 2);
        ss += __shfl_xor(ss, 1); ss += __shfl_xor(ss, 2);
        const float mean = s * (1.f/128.f);
        const float var  = ss * (1.f/128.f) - mean*mean;
        const float rstd = rsqrtf(var + EPS_F);
        const float4* wz4 = (const float4*)wz;
        float4 zacc = make_float4(0.f,0.f,0.f,0.f);
        #pragma unroll
        for (int i2 = 0; i2 < 8; i2++) {
            float4 w4 = ((const float4*)(lnw + c0))[i2];
            float4 b4 = ((const float4*)(lnb + c0))[i2];
            float4 r4;
            r4.x = (xv[i2].x - mean)*rstd*w4.x + b4.x;
            r4.y = (xv[i2].y - mean)*rstd*w4.y + b4.y;
            r4.z = (xv[i2].z - mean)*rstd*w4.z + b4.z;
            r4.w = (xv[i2].w - mean)*rstd*w4.w + b4.w;
            const float4 za = wz4[c0 + i2*4 + 0];
            const float4 zb_ = wz4[c0 + i2*4 + 1];
            const float4 zc = wz4[c0 + i2*4 + 2];
            const float4 zd = wz4[c0 + i2*4 + 3];
            zacc.x += r4.x*za.x + r4.y*zb_.x + r4.z*zc.x + r4.w*zd.x;
            zacc.y += r4.x*za.y + r4.y*zb_.y + r4.z*zc.y + r4.w*zd.y;
            zacc.z += r4.x*za.z + r4.y*zb_.z + r4.z*zc.z + r4.w*zd.z;
            zacc.w += r4.x*za.w + r4.y*zb_.w + r4.z*zc.w + r4.w*zd.w;
            const int wi = r*64 + qt*16 + i2*2;
            xs[(wi  ) ^ sw] = pk2(r4.x, r4.y);
            xs[(wi+1) ^ sw] = pk2(r4.z, r4.w);
            xv[i2] = r4;
        }
        zacc.x += __shfl_xor(zacc.x, 1); zacc.x += __shfl_xor(zacc.x, 2);
        zacc.y += __shfl_xor(zacc.y, 1); zacc.y += __shfl_xor(zacc.y, 2);
        zacc.z += __shfl_xor(zacc.z, 1); zacc.z += __shfl_xor(zacc.z, 2);
        zacc.w += __shfl_xor(zacc.w, 1); zacc.w += __shfl_xor(zacc.w, 2);
        const float zv = (qt==0)?zacc.x:(qt==1)?zacc.y:(qt==2)?zacc.z:zacc.w;
        zo[(size_t)qt*M_DIM + row0 + r] = (zv + bz[qt]) * LOG2E_F;
    }
    __syncthreads();

    U4S8 ah[4], al[4];
    const int arow = w*16 + n16;
    #pragma unroll
    for (int ks = 0; ks < 4; ++ks) {
        const int bofs = arow*256 + ((ks*64 + quad*16) ^ ((arow & 7) << 4));
        ah[ks].u = *(const uint4*)((const char*)xs + bofs);
    }
    __syncthreads();

    #pragma unroll
    for (int i2 = 0; i2 < 8; i2++) {
        const float4 r4 = xv[i2];
        const unsigned short h0 = f2bf(r4.x), h1 = f2bf(r4.y),
                             h2 = f2bf(r4.z), h3 = f2bf(r4.w);
        const int wi = r*64 + qt*16 + i2*2;
        xs[(wi  ) ^ sw] = (unsigned int)f2bf(r4.x - bf2f(h0))
                        | ((unsigned int)f2bf(r4.y - bf2f(h1)) << 16);
        xs[(wi+1) ^ sw] = (unsigned int)f2bf(r4.z - bf2f(h2))
                        | ((unsigned int)f2bf(r4.w - bf2f(h3)) << 16);
    }
    __syncthreads();
    #pragma unroll
    for (int ks = 0; ks < 4; ++ks) {
        const int bofs = arow*256 + ((ks*64 + quad*16) ^ ((arow & 7) << 4));
        al[ks].u = *(const uint4*)((const char*)xs + bofs);
    }

    const int i_blk = row0 / I_DIM;
    const int jp0   = (row0 % I_DIM) >> 1;
    const int rw0   = row0 + w*16 + quad*4;

    int p = 0;
    #pragma unroll
    for (int rd = 0; rd < 16; ++rd) {
        const int mi = rd >> 2, qq = rd & 3;

        // ---- stage NEXT quarter into the other buffer (latency hidden) ----
        if (rd < 15) {
            const int m2 = (rd+1) >> 2, q2 = (rd+1) & 3;
            #pragma unroll
            for (int it = 0; it < 4; ++it) {
                const int tl = w*4 + it;
                const int s = tl >> 3, ntl2 = (tl >> 2) & 1, ks = tl & 3;
                load_lds16(wfmt_dev + (size_t)m2*4096
                           + (size_t)((s*8 + (q2*2 + ntl2))*4 + ks)*64 + l,
                           (char*)wbuf4 + (p^1)*16384 + tl*1024);
            }
        }

        f32x4 acc[2];
        #pragma unroll
        for (int ntl = 0; ntl < 2; ++ntl) {
            f32x4 a = {0.f, 0.f, 0.f, 0.f};
            #pragma unroll
            for (int ks = 0; ks < 4; ++ks) {
                U4S8 bh, bl;
                bh.u = wbuf4[p*1024 + (    ntl*4 + ks)*64 + l];
                bl.u = wbuf4[p*1024 + (8 + ntl*4 + ks)*64 + l];
                a = __builtin_amdgcn_mfma_f32_16x16x32_bf16(ah[ks].s, bh.s, a, 0,0,0);
                a = __builtin_amdgcn_mfma_f32_16x16x32_bf16(al[ks].s, bh.s, a, 0,0,0);
                a = __builtin_amdgcn_mfma_f32_16x16x32_bf16(ah[ks].s, bl.s, a, 0,0,0);
            }
            acc[ntl] = a;
        }

        if (mi == 0) {                 // q bf16 row-major (same RNE as before)
            #pragma unroll
            for (int ntl = 0; ntl < 2; ++ntl)
                #pragma unroll
                for (int rr = 0; rr < 4; ++rr)
                    qo16[(size_t)(rw0 + rr)*C_DIM + qq*32 + ntl*16 + n16] =
                        f2bf(acc[ntl][rr]);
        } else if (mi == 1) {
            #pragma unroll
            for (int ntl = 0; ntl < 2; ++ntl)
                #pragma unroll
                for (int rr = 0; rr < 4; ++rr)
                    ko16[(size_t)(rw0 + rr)*C_DIM + qq*32 + ntl*16 + n16] =
                        f2bf(acc[ntl][rr]);
        } else if (mi == 2) {
            #pragma unroll
            for (int ntl = 0; ntl < 2; ++ntl) {
                const float bgv = bg[qq*32 + ntl*16 + n16];
                #pragma unroll
                for (int rr = 0; rr < 4; ++rr)
                    go[(size_t)(rw0 + rr)*C_DIM + qq*32 + ntl*16 + n16] =
                        1.f/(1.f + __expf(-(acc[ntl][rr] + bgv)));
            }
        } else {
            #pragma unroll
            for (int ntl = 0; ntl < 2; ++ntl)
                #pragma unroll
                for (int pr = 0; pr < 2; ++pr)
                    vts[(ntl*16 + n16)*33 + w*8 + quad*2 + pr] =
                        pk2(acc[ntl][2*pr], acc[ntl][2*pr+1]);
            __syncthreads();
            for (int idx = t; idx < 32*32; idx += 256) {
                const int ch_l = idx >> 5, pp = idx & 31;
                vto[((size_t)i_blk*C_DIM + qq*32 + ch_l)*192 + jp0 + pp] =
                    vts[ch_l*33 + pp];
            }
        }

        __syncthreads();      // drains stage + stores; next round reads p^1
        p ^= 1;
    }
}

// ---------------------------------------------------------------------------
// Kernel 2: MFMA attention (round-10 verified math). Changes:
//  - K fragments REGISTER-RESIDENT: loaded once per wave from global before
//    the qt loop (frags are qt-invariant). Ks4 LDS + staging deleted.
//  - V^T in fragment-linear LDS VTf[24][64]: reading lane l reads slot l ->
//    stride-16B conflict-free ds_read_b128 (replaces stride-49 8-way layout).
//  - c-loop unroll 1 (frees live-range pressure for the 96 K VGPRs).
// LDS 26.1 KB. Same values, same MFMA order -> bit-identical output.
// ---------------------------------------------------------------------------
__global__ __launch_bounds__(256, 3) void attn_mfma_kernel(
    const unsigned short* __restrict__ q16, const unsigned short* __restrict__ k16,
    const unsigned int* __restrict__ vt32, const float* __restrict__ zb,
    const float* __restrict__ mask, const float* g, unsigned int* og)
{
    __shared__ uint4 VTf[24*64];              // 24576 B fragment-linear V^T
    __shared__ __align__(16) float mbl[384];  // 1536 B (pre-scaled by LOG2E)

    const int ii = blockIdx.x;
    const int h  = blockIdx.y;
    const int t  = threadIdx.x;
    const size_t rbase = (size_t)ii*I_DIM*C_DIM + h*HD_DIM;

    // ---- stage V^T fragments (coalesced global read, scattered LDS write) ----
    for (int idx = t; idx < 1536; idx += 256) {
        const int d = idx / 48, m = idx - d*48;   // d: head-slice row 0..31
        const int hh = d >> 4, nn = d & 15;
        const int c = m / 12, rem = m - c*12;
        const int km = rem >> 2, qd = rem & 3;
        VTf[(c*6 + km*2 + hh)*64 + qd*16 + nn] =
            ((const uint4*)vt32)[((size_t)ii*C_DIM + h*HD_DIM + d)*48 + m];
    }
    for (int jj = t; jj < 384; jj += 256)
        mbl[jj] = (INF_F*LOG2E_F) * (mask[(size_t)ii*I_DIM + jj] - 1.f);
    __syncthreads();

    const int w = t >> 6, l = t & 63;
    const int n16 = l & 15, quad = l >> 4;
    const int slA = n16 + ((quad & 1) << 5);   // source lane: quad' = 2*(quad&1)
    const int slB = slA + 16;                  // quad' + 1
    const bool hi = (quad & 2) != 0;           // selects k6 = 2km+1

    // ---- K fragments register-resident (qt-invariant; shared via L2) ----
    U4S8 kb[24];
    #pragma unroll
    for (int kt = 0; kt < 24; ++kt)
        kb[kt].u = *(const uint4*)(k16 + rbase
                       + (size_t)(kt*16 + n16)*C_DIM + quad*8);

    #pragma unroll 1
    for (int qt = 0; qt < 6; qt++) {
        const int qg = w*6 + qt;               // q rows qg*16..+15

        // ---- Q-frag (B-operand): bf16 row-major, single 16B load ----
        U4S8 a;
        a.u = *(const uint4*)(q16 + rbase + (size_t)(qg*16 + n16)*C_DIM + quad*8);

        f32x4 oacc0 = {0.f,0.f,0.f,0.f}, oacc1 = {0.f,0.f,0.f,0.f};
        float lsum = 0.f;
        const float* zrow = zb + (size_t)h*M_DIM
                          + (size_t)(qg*16 + n16)*I_DIM + quad*4;

        #pragma unroll 1
        for (int c = 0; c < 4; c++) {
            // C-init = z + mask bias (rides the MFMA C-operand for free)
            f32x4 cin[6];
            #pragma unroll
            for (int k6 = 0; k6 < 6; k6++) {
                const float4 z4 = *(const float4*)&zrow[96*c + k6*16];
                const float4 m4 = *(const float4*)&mbl[96*c + k6*16 + quad*4];
                cin[k6][0] = z4.x + m4.x;
                cin[k6][1] = z4.y + m4.y;
                cin[k6][2] = z4.z + m4.z;
                cin[k6][3] = z4.w + m4.w;
            }

            // ---- QK^T swapped, biased: accS = K·Q + (z+mask), K from regs ----
            f32x4 accS[6];
            __builtin_amdgcn_s_setprio(1);
            #pragma unroll
            for (int k6 = 0; k6 < 6; k6++)
                accS[k6] = __builtin_amdgcn_mfma_f32_16x16x32_bf16(
                    kb[c*6 + k6].s, a.s, cin[k6], 0, 0, 0);
            __builtin_amdgcn_s_setprio(0);

            // ---- exp2 + lane-local sum + pack to bf16 pairs ----
            unsigned int pu[6][2];
            #pragma unroll
            for (int k6 = 0; k6 < 6; k6++) {
                const float e0 = __builtin_amdgcn_exp2f(accS[k6][0]);
                const float e1 = __builtin_amdgcn_exp2f(accS[k6][1]);
                const float e2 = __builtin_amdgcn_exp2f(accS[k6][2]);
                const float e3 = __builtin_amdgcn_exp2f(accS[k6][3]);
                lsum += (e0 + e1) + (e2 + e3);
                pu[k6][0] = cvtpk(e0, e1);
                pu[k6][1] = cvtpk(e2, e3);
            }

            // ---- exchange (fixed quad permutation) + PV ----
            #pragma unroll
            for (int km = 0; km < 3; km++) {
                const unsigned int x0 = __shfl((int)pu[2*km  ][0], slA);
                const unsigned int x1 = __shfl((int)pu[2*km+1][0], slA);
                const unsigned int y0 = __shfl((int)pu[2*km  ][1], slA);
                const unsigned int y1 = __shfl((int)pu[2*km+1][1], slA);
                const unsigned int z0 = __shfl((int)pu[2*km  ][0], slB);
                const unsigned int z1 = __shfl((int)pu[2*km+1][0], slB);
                const unsigned int w0 = __shfl((int)pu[2*km  ][1], slB);
                const unsigned int w1 = __shfl((int)pu[2*km+1][1], slB);
                U4S8 pa;
                pa.u = make_uint4(hi?x1:x0, hi?y1:y0, hi?z1:z0, hi?w1:w0);
                U4S8 vb0, vb1;
                vb0.u = VTf[(c*6 + km*2    )*64 + l];
                vb1.u = VTf[(c*6 + km*2 + 1)*64 + l];
                __builtin_amdgcn_s_setprio(1);
                oacc0 = __builtin_amdgcn_mfma_f32_16x16x32_bf16(vb0.s, pa.s, oacc0, 0,0,0);
                oacc1 = __builtin_amdgcn_mfma_f32_16x16x32_bf16(vb1.s, pa.s, oacc1, 0,0,0);
                __builtin_amdgcn_s_setprio(0);
            }
        }

        // ---- normalize, fuse gate, store hi/lo pairs ----
        float s_ = lsum;
        s_ += __shfl_xor(s_, 16);
        s_ += __shfl_xor(s_, 32);
        const float rcp = 1.f / s_;
        const size_t orow = rbase + (size_t)(qg*16 + n16)*C_DIM;
        const float4 g0 = *(const float4*)&g[orow + quad*4];
        const float4 g1 = *(const float4*)&g[orow + 16 + quad*4];
        const float o00 = oacc0[0]*rcp, o01 = oacc0[1]*rcp,
                    o02 = oacc0[2]*rcp, o03 = oacc0[3]*rcp;
        const float o10 = oacc1[0]*rcp, o11 = oacc1[1]*rcp,
                    o12 = oacc1[2]*rcp, o13 = oacc1[3]*rcp;
        uint4 w0_, w1_;
        w0_.x = hl32(o00*g0.x); w0_.y = hl32(o01*g0.y);
        w0_.z = hl32(o02*g0.z); w0_.w = hl32(o03*g0.w);
        w1_.x = hl32(o10*g1.x); w1_.y = hl32(o11*g1.y);
        w1_.z = hl32(o12*g1.z); w1_.w = hl32(o13*g1.w);
        *(uint4*)&og[orow + quad*4]      = w0_;
        *(uint4*)&og[orow + 16 + quad*4] = w1_;
    }
}

// ---------------------------------------------------------------------------
// Kernel 3: out = p @ wo + bo where p = o*g arrives PRE-SPLIT as hi/lo bf16
// pairs (uint/elem) from attention. (round-10 verified version, unchanged.)
// ---------------------------------------------------------------------------
__global__ __launch_bounds__(256, 3) void out_proj_kernel(
    const unsigned int* __restrict__ og,
    const float* __restrict__ bo, float* out)
{
    __shared__ __align__(16) unsigned int xs[4096];
    __shared__ __align__(16) uint4 wbuf4[2048];       // 2 x 16KB dbuf
    const int t    = threadIdx.x;
    const int row0 = blockIdx.x * 64;
    const int w = t >> 6, l = t & 63, n16 = l & 15, quad = l >> 4;

    // prefetch wo quarter 0 -> buffer 0
    #pragma unroll
    for (int it = 0; it < 4; ++it) {
        const int tl = w*4 + it;
        const int s = tl >> 3, ntl = (tl >> 2) & 1, ks = tl & 3;
        load_lds16(wfmt_dev + (size_t)4*4096 + (size_t)((s*8 + ntl)*4 + ks)*64 + l,
                   (char*)wbuf4 + tl*1024);
    }

    uint4 pw[8];                       // 32 packed hi|lo elems
    const int r = t >> 2, qt = t & 3, c0 = qt * 32;
    const int sw = (r & 7) << 2;
    {
        const uint4* prow = (const uint4*)(og + (size_t)(row0 + r)*C_DIM + c0);
        #pragma unroll
        for (int i2 = 0; i2 < 8; i2++) {
            pw[i2] = prow[i2];
            const int wi = r*64 + qt*16 + i2*2;
            xs[(wi  ) ^ sw] = (pw[i2].x & 0xffffu) | (pw[i2].y << 16);
            xs[(wi+1) ^ sw] = (pw[i2].z & 0xffffu) | (pw[i2].w << 16);
        }
    }
    __syncthreads();

    U4S8 ah[4], al[4];
    const int arow = w*16 + n16;
    #pragma unroll
    for (int ks = 0; ks < 4; ++ks) {
        const int bofs = arow*256 + ((ks*64 + quad*16) ^ ((arow & 7) << 4));
        ah[ks].u = *(const uint4*)((const char*)xs + bofs);
    }
    __syncthreads();
    #pragma unroll
    for (int i2 = 0; i2 < 8; i2++) {
        const int wi = r*64 + qt*16 + i2*2;
        xs[(wi  ) ^ sw] = (pw[i2].x >> 16) | (pw[i2].y & 0xffff0000u);
        xs[(wi+1) ^ sw] = (pw[i2].z >> 16) | (pw[i2].w & 0xffff0000u);
    }
    __syncthreads();
    #pragma unroll
    for (int ks = 0; ks < 4; ++ks) {
        const int bofs = arow*256 + ((ks*64 + quad*16) ^ ((arow & 7) << 4));
        al[ks].u = *(const uint4*)((const char*)xs + bofs);
    }

    const int rw0 = row0 + w*16 + quad*4;
    int p = 0;
    #pragma unroll
    for (int qq = 0; qq < 4; ++qq) {
        if (qq < 3) {
            const int q2 = qq + 1;
            #pragma unroll
            for (int it = 0; it < 4; ++it) {
                const int tl = w*4 + it;
                const int s = tl >> 3, ntl2 = (tl >> 2) & 1, ks = tl & 3;
                load_lds16(wfmt_dev + (size_t)4*4096
                           + (size_t)((s*8 + (q2*2 + ntl2))*4 + ks)*64 + l,
                           (char*)wbuf4 + (p^1)*16384 + tl*1024);
            }
        }
        f32x4 acc[2];
        #pragma unroll
        for (int ntl = 0; ntl < 2; ++ntl) {
            f32x4 a = {0.f, 0.f, 0.f, 0.f};
            #pragma unroll
            for (int ks = 0; ks < 4; ++ks) {
                U4S8 bh, bl;
                bh.u = wbuf4[p*1024 + (    ntl*4 + ks)*64 + l];
                bl.u = wbuf4[p*1024 + (8 + ntl*4 + ks)*64 + l];
                a = __builtin_amdgcn_mfma_f32_16x16x32_bf16(ah[ks].s, bh.s, a, 0,0,0);
                a = __builtin_amdgcn_mfma_f32_16x16x32_bf16(al[ks].s, bh.s, a, 0,0,0);
                a = __builtin_amdgcn_mfma_f32_16x16x32_bf16(ah[ks].s, bl.s, a, 0,0,0);
            }
            acc[ntl] = a;
        }
        #pragma unroll
        for (int ntl = 0; ntl < 2; ++ntl) {
            const int n = qq*32 + ntl*16 + n16;
            const float bov = bo[n];
            #pragma unroll
            for (int rr = 0; rr < 4; ++rr)
                out[(size_t)(rw0 + rr)*C_DIM + n] = acc[ntl][rr] + bov;
        }
        __syncthreads();
        p ^= 1;
    }
}

extern "C" void kernel_launch(void* const* d_in, const int* in_sizes, int n_in,
                              void* d_out, int out_size, void* d_ws, size_t ws_size,
                              hipStream_t stream)
{
    (void)in_sizes; (void)n_in; (void)out_size; (void)ws_size;
    const float* x    = (const float*)d_in[0];
    const float* mask = (const float*)d_in[1];
    const float* lnw  = (const float*)d_in[2];
    const float* lnb  = (const float*)d_in[3];
    const float* wz   = (const float*)d_in[4];
    const float* bz   = (const float*)d_in[5];
    const float* wq   = (const float*)d_in[6];
    const float* wk   = (const float*)d_in[7];
    const float* wv   = (const float*)d_in[8];
    const float* wg   = (const float*)d_in[9];
    const float* bg   = (const float*)d_in[10];
    const float* wo   = (const float*)d_in[11];
    const float* bo   = (const float*)d_in[12];

    // ws layout (offsets unchanged; q region holds bf16, o*g lives in d_out):
    //   qb   region M*128 fp32-sized; q bf16 uses first half
    //   zbuf fp32 4*M    (pre-scaled by LOG2E)
    //   kb16 bf16 M*128 row-major
    //   vt32 bf16 M*128 transposed [i][c][j], packed uint pairs along j
    float* ws = (float*)d_ws;
    float* qb   = ws;
    float* zbuf = qb + (size_t)M_DIM*C_DIM;
    unsigned short* kb16 = (unsigned short*)(zbuf + (size_t)H_NUM*M_DIM);
    unsigned int*   vt32 = (unsigned int*)(kb16 + (size_t)M_DIM*C_DIM);
    unsigned short* q16  = (unsigned short*)qb;
    float* gbuf = (float*)d_out;     // g parked in d_out; attn replaces it
                                     // in-place with packed (o*g) hi/lo pairs

    wprep_kernel<<<80, 256, 0, stream>>>(wq, wk, wg, wv, wo);
    ln_proj_kernel<<<M_DIM/64, 256, 0, stream>>>(
        x, lnw, lnb, wz, bz, bg, q16, kb16, vt32, gbuf, zbuf);
    attn_mfma_kernel<<<dim3(I_DIM, H_NUM), 256, 0, stream>>>(
        q16, kb16, vt32, zbuf, mask, gbuf, (unsigned int*)d_out);
    out_proj_kernel<<<M_DIM/64, 256, 0, stream>>>(
        (const unsigned int*)d_out, bo, (float*)d_out);
}

// Round 12
// 413.396 us; speedup vs baseline: 1.4626x; 1.4626x over previous
//
#include <hip/hip_runtime.h>
#include <math.h>

#define I_DIM 384
#define C_DIM 128
#define H_NUM 4
#define HD_DIM 32
#define M_DIM (I_DIM*I_DIM)       // 147456
#define INF_F 1000000000.0f
#define EPS_F 1e-5f
#define QSCALE 0.17677669529663687f   // 1/sqrt(32)
#define LOG2E_F 1.4426950408889634f

typedef __attribute__((ext_vector_type(8))) short short8;
typedef __attribute__((ext_vector_type(4))) float f32x4;
union U4S8 { uint4 u; short8 s; };

__device__ __forceinline__ unsigned short f2bf(float f) {
    unsigned int u = __float_as_uint(f);
    u += 0x7fffu + ((u >> 16) & 1u);          // round-to-nearest-even
    return (unsigned short)(u >> 16);
}
__device__ __forceinline__ float bf2f(unsigned short h) {
    return __uint_as_float((unsigned int)h << 16);
}
__device__ __forceinline__ unsigned int pk2(float a, float b) {
    return (unsigned int)f2bf(a) | ((unsigned int)f2bf(b) << 16);
}
// HW packed f32->bf16 (RNE)
__device__ __forceinline__ unsigned int cvtpk(float lo, float hi) {
    unsigned int r;
    asm("v_cvt_pk_bf16_f32 %0, %1, %2" : "=v"(r) : "v"(lo), "v"(hi));
    return r;
}
// hi/lo split of one fp32 into a single uint: hi bf16 in low16, lo bf16 in hi16
__device__ __forceinline__ unsigned int hl32(float v) {
    const unsigned short h = f2bf(v);
    const unsigned short lo = f2bf(v - bf2f(h));
    return (unsigned int)h | ((unsigned int)lo << 16);
}

// ---------------------------------------------------------------------------
// Pre-formatted split weights, MFMA-B-fragment-linear:
//   wfmt_dev[mat(5)][s(2)][nt(8)][ks(4)][lane(64)] : uint4 (8 bf16, k-consec)
//   mats: 0=wq (pre-scaled by QSCALE*LOG2E), 1=wk, 2=wg, 3=wv, 4=wo
//   s=0: bf16(w); s=1: bf16(w - bf16(w))   (hi/lo split, ~fp32 when summed)
// ---------------------------------------------------------------------------
__device__ uint4 wfmt_dev[5*4096];     // 320 KB static device memory

__device__ __forceinline__ void load_lds16(const uint4* gp, void* lp) {
    __builtin_amdgcn_global_load_lds(
        (const __attribute__((address_space(1))) unsigned int*)gp,
        (__attribute__((address_space(3))) unsigned int*)lp,
        16, 0, 0);
}

__global__ __launch_bounds__(256) void wprep_kernel(
    const float* __restrict__ wq, const float* __restrict__ wk,
    const float* __restrict__ wg, const float* __restrict__ wv,
    const float* __restrict__ wo)
{
    const int tid  = blockIdx.x*256 + threadIdx.x;   // 80 blocks -> 320 tiles
    const int l    = tid & 63, tile = tid >> 6;
    const int ks   = tile & 3, nt = (tile >> 2) & 7;
    const int s    = (tile >> 5) & 1, m = tile >> 6;
    const float* W = (m==0)?wq:(m==1)?wk:(m==2)?wg:(m==3)?wv:wo;
    const float scale = (m==0) ? QSCALE*LOG2E_F : 1.f;  // fold exp2 conversion
    const int n  = nt*16 + (l & 15);
    const int kb = ks*32 + (l >> 4)*8;
    unsigned int hw[4];
    #pragma unroll
    for (int jp = 0; jp < 4; ++jp) {
        unsigned short hs[2];
        #pragma unroll
        for (int e = 0; e < 2; ++e) {
            float v = W[(size_t)(kb + jp*2 + e)*C_DIM + n] * scale;
            unsigned short h = f2bf(v);
            if (s) h = f2bf(v - bf2f(h));
            hs[e] = h;
        }
        hw[jp] = (unsigned int)hs[0] | ((unsigned int)hs[1] << 16);
    }
    wfmt_dev[(size_t)m*4096 + (size_t)((s*8 + nt)*4 + ks)*64 + l] =
        make_uint4(hw[0], hw[1], hw[2], hw[3]);
}

// ---------------------------------------------------------------------------
// Kernel 1: LayerNorm + z head + q/k/v/g projections via split-bf16 MFMA.
// (round-10 verified version, unchanged.)
// ---------------------------------------------------------------------------
__global__ __launch_bounds__(256, 3) void ln_proj_kernel(
    const float* __restrict__ x,
    const float* __restrict__ lnw, const float* __restrict__ lnb,
    const float* __restrict__ wz,  const float* __restrict__ bz,
    const float* __restrict__ bg,
    unsigned short* __restrict__ qo16, unsigned short* __restrict__ ko16,
    unsigned int* __restrict__ vto, float* __restrict__ go,
    float* __restrict__ zo)
{
    __shared__ __align__(16) unsigned int xs[4096];   // 16KB: hi, lo, then vts
    __shared__ __align__(16) uint4 wbuf4[2048];       // 2 x 16KB quarter dbuf
    unsigned int* vts = xs;

    const int t    = threadIdx.x;
    const int row0 = blockIdx.x * 64;
    const int w = t >> 6, l = t & 63, n16 = l & 15, quad = l >> 4;

    // ---- prefetch round 0 (wq, quarter 0) into buffer 0 ----
    #pragma unroll
    for (int it = 0; it < 4; ++it) {
        const int tl = w*4 + it;
        const int s = tl >> 3, ntl = (tl >> 2) & 1, ks = tl & 3;
        load_lds16(wfmt_dev + (size_t)((s*8 + ntl)*4 + ks)*64 + l,
                   (char*)wbuf4 + tl*1024);
    }

    // ---- Phase A: LayerNorm + z head; LN results kept in registers ----
    float4 xv[8];
    const int r = t >> 2, qt = t & 3, c0 = qt * 32;
    const int sw = (r & 7) << 2;
    {
        const float* xrow = x + (size_t)(row0 + r)*C_DIM + c0;
        float s = 0.f, ss = 0.f;
        #pragma unroll
        for (int i2 = 0; i2 < 8; i2++) {
            xv[i2] = ((const float4*)xrow)[i2];
            s  += xv[i2].x + xv[i2].y + xv[i2].z + xv[i2].w;
            ss += xv[i2].x*xv[i2].x + xv[i2].y*xv[i2].y
                + xv[i2].z*xv[i2].z + xv[i2].w*xv[i2].w;
        }
        s  += __shfl_xor(s, 1);  s  += __shfl_xor(s, 2);
        ss += __shfl_xor(ss, 1); ss += __shfl_xor(ss, 2);
        const float mean = s * (1.f/128.f);
        const float var  = ss * (1.f/128.f) - mean*mean;
        const float rstd = rsqrtf(var + EPS_F);
        const float4* wz4 = (const float4*)wz;
        float4 zacc = make_float4(0.f,0.f,0.f,0.f);
        #pragma unroll
        for (int i2 = 0; i2 < 8; i2++) {
            float4 w4 = ((const float4*)(lnw + c0))[i2];
            float4 b4 = ((const float4*)(lnb + c0))[i2];
            float4 r4;
            r4.x = (xv[i2].x - mean)*rstd*w4.x + b4.x;
            r4.y = (xv[i2].y - mean)*rstd*w4.y + b4.y;
            r4.z = (xv[i2].z - mean)*rstd*w4.z + b4.z;
            r4.w = (xv[i2].w - mean)*rstd*w4.w + b4.w;
            const float4 za = wz4[c0 + i2*4 + 0];
            const float4 zb_ = wz4[c0 + i2*4 + 1];
            const float4 zc = wz4[c0 + i2*4 + 2];
            const float4 zd = wz4[c0 + i2*4 + 3];
            zacc.x += r4.x*za.x + r4.y*zb_.x + r4.z*zc.x + r4.w*zd.x;
            zacc.y += r4.x*za.y + r4.y*zb_.y + r4.z*zc.y + r4.w*zd.y;
            zacc.z += r4.x*za.z + r4.y*zb_.z + r4.z*zc.z + r4.w*zd.z;
            zacc.w += r4.x*za.w + r4.y*zb_.w + r4.z*zc.w + r4.w*zd.w;
            const int wi = r*64 + qt*16 + i2*2;
            xs[(wi  ) ^ sw] = pk2(r4.x, r4.y);
            xs[(wi+1) ^ sw] = pk2(r4.z, r4.w);
            xv[i2] = r4;
        }
        zacc.x += __shfl_xor(zacc.x, 1); zacc.x += __shfl_xor(zacc.x, 2);
        zacc.y += __shfl_xor(zacc.y, 1); zacc.y += __shfl_xor(zacc.y, 2);
        zacc.z += __shfl_xor(zacc.z, 1); zacc.z += __shfl_xor(zacc.z, 2);
        zacc.w += __shfl_xor(zacc.w, 1); zacc.w += __shfl_xor(zacc.w, 2);
        const float zv = (qt==0)?zacc.x:(qt==1)?zacc.y:(qt==2)?zacc.z:zacc.w;
        zo[(size_t)qt*M_DIM + row0 + r] = (zv + bz[qt]) * LOG2E_F;
    }
    __syncthreads();

    U4S8 ah[4], al[4];
    const int arow = w*16 + n16;
    #pragma unroll
    for (int ks = 0; ks < 4; ++ks) {
        const int bofs = arow*256 + ((ks*64 + quad*16) ^ ((arow & 7) << 4));
        ah[ks].u = *(const uint4*)((const char*)xs + bofs);
    }
    __syncthreads();

    #pragma unroll
    for (int i2 = 0; i2 < 8; i2++) {
        const float4 r4 = xv[i2];
        const unsigned short h0 = f2bf(r4.x), h1 = f2bf(r4.y),
                             h2 = f2bf(r4.z), h3 = f2bf(r4.w);
        const int wi = r*64 + qt*16 + i2*2;
        xs[(wi  ) ^ sw] = (unsigned int)f2bf(r4.x - bf2f(h0))
                        | ((unsigned int)f2bf(r4.y - bf2f(h1)) << 16);
        xs[(wi+1) ^ sw] = (unsigned int)f2bf(r4.z - bf2f(h2))
                        | ((unsigned int)f2bf(r4.w - bf2f(h3)) << 16);
    }
    __syncthreads();
    #pragma unroll
    for (int ks = 0; ks < 4; ++ks) {
        const int bofs = arow*256 + ((ks*64 + quad*16) ^ ((arow & 7) << 4));
        al[ks].u = *(const uint4*)((const char*)xs + bofs);
    }

    const int i_blk = row0 / I_DIM;
    const int jp0   = (row0 % I_DIM) >> 1;
    const int rw0   = row0 + w*16 + quad*4;

    int p = 0;
    #pragma unroll
    for (int rd = 0; rd < 16; ++rd) {
        const int mi = rd >> 2, qq = rd & 3;

        // ---- stage NEXT quarter into the other buffer (latency hidden) ----
        if (rd < 15) {
            const int m2 = (rd+1) >> 2, q2 = (rd+1) & 3;
            #pragma unroll
            for (int it = 0; it < 4; ++it) {
                const int tl = w*4 + it;
                const int s = tl >> 3, ntl2 = (tl >> 2) & 1, ks = tl & 3;
                load_lds16(wfmt_dev + (size_t)m2*4096
                           + (size_t)((s*8 + (q2*2 + ntl2))*4 + ks)*64 + l,
                           (char*)wbuf4 + (p^1)*16384 + tl*1024);
            }
        }

        f32x4 acc[2];
        #pragma unroll
        for (int ntl = 0; ntl < 2; ++ntl) {
            f32x4 a = {0.f, 0.f, 0.f, 0.f};
            #pragma unroll
            for (int ks = 0; ks < 4; ++ks) {
                U4S8 bh, bl;
                bh.u = wbuf4[p*1024 + (    ntl*4 + ks)*64 + l];
                bl.u = wbuf4[p*1024 + (8 + ntl*4 + ks)*64 + l];
                a = __builtin_amdgcn_mfma_f32_16x16x32_bf16(ah[ks].s, bh.s, a, 0,0,0);
                a = __builtin_amdgcn_mfma_f32_16x16x32_bf16(al[ks].s, bh.s, a, 0,0,0);
                a = __builtin_amdgcn_mfma_f32_16x16x32_bf16(ah[ks].s, bl.s, a, 0,0,0);
            }
            acc[ntl] = a;
        }

        if (mi == 0) {                 // q bf16 row-major (same RNE as before)
            #pragma unroll
            for (int ntl = 0; ntl < 2; ++ntl)
                #pragma unroll
                for (int rr = 0; rr < 4; ++rr)
                    qo16[(size_t)(rw0 + rr)*C_DIM + qq*32 + ntl*16 + n16] =
                        f2bf(acc[ntl][rr]);
        } else if (mi == 1) {
            #pragma unroll
            for (int ntl = 0; ntl < 2; ++ntl)
                #pragma unroll
                for (int rr = 0; rr < 4; ++rr)
                    ko16[(size_t)(rw0 + rr)*C_DIM + qq*32 + ntl*16 + n16] =
                        f2bf(acc[ntl][rr]);
        } else if (mi == 2) {
            #pragma unroll
            for (int ntl = 0; ntl < 2; ++ntl) {
                const float bgv = bg[qq*32 + ntl*16 + n16];
                #pragma unroll
                for (int rr = 0; rr < 4; ++rr)
                    go[(size_t)(rw0 + rr)*C_DIM + qq*32 + ntl*16 + n16] =
                        1.f/(1.f + __expf(-(acc[ntl][rr] + bgv)));
            }
        } else {
            #pragma unroll
            for (int ntl = 0; ntl < 2; ++ntl)
                #pragma unroll
                for (int pr = 0; pr < 2; ++pr)
                    vts[(ntl*16 + n16)*33 + w*8 + quad*2 + pr] =
                        pk2(acc[ntl][2*pr], acc[ntl][2*pr+1]);
            __syncthreads();
            for (int idx = t; idx < 32*32; idx += 256) {
                const int ch_l = idx >> 5, pp = idx & 31;
                vto[((size_t)i_blk*C_DIM + qq*32 + ch_l)*192 + jp0 + pp] =
                    vts[ch_l*33 + pp];
            }
        }

        __syncthreads();      // drains stage + stores; next round reads p^1
        p ^= 1;
    }
}

// ---------------------------------------------------------------------------
// Kernel 2: MFMA attention. Round-10 verified structure (Ks4 swizzled LDS,
// unroll-2 c-loop, bias-in-C, exp2, fused o*g epilogue) with ONE change:
// V^T in fragment-linear LDS VTf[24][64] (verified correct in round 11) —
// reading lane l reads slot l -> conflict-free ds_read_b128, replacing the
// stride-49 8-way-conflicted VTl. LDS 50.7 KB -> 3 blocks/CU (unchanged).
// ---------------------------------------------------------------------------
__global__ __launch_bounds__(256, 3) void attn_mfma_kernel(
    const unsigned short* __restrict__ q16, const unsigned short* __restrict__ k16,
    const unsigned int* __restrict__ vt32, const float* __restrict__ zb,
    const float* __restrict__ mask, const float* g, unsigned int* og)
{
    __shared__ uint4 Ks4[384*4];              // K rows bf16, swizzled: 24576 B
    __shared__ uint4 VTf[24*64];              // fragment-linear V^T: 24576 B
    __shared__ __align__(16) float mbl[384];  // 1536 B (pre-scaled by LOG2E)

    const int ii = blockIdx.x;
    const int h  = blockIdx.y;
    const int t  = threadIdx.x;
    const size_t rbase = (size_t)ii*I_DIM*C_DIM + h*HD_DIM;

    // ---- stage K (swizzled slots) and V^T (fragment-linear) ----
    for (int idx = t; idx < 1536; idx += 256) {
        const int j = idx >> 2, c4 = idx & 3;
        Ks4[j*4 + (c4 ^ ((j >> 1) & 3))] =
            ((const uint4*)k16)[rbase/8 + (size_t)j*16 + c4];
    }
    for (int idx = t; idx < 1536; idx += 256) {
        const int d = idx / 48, m = idx - d*48;   // d: head-slice row 0..31
        const int hh = d >> 4, nn = d & 15;
        const int c = m / 12, rem = m - c*12;
        const int km = rem >> 2, qd = rem & 3;
        VTf[(c*6 + km*2 + hh)*64 + qd*16 + nn] =
            ((const uint4*)vt32)[((size_t)ii*C_DIM + h*HD_DIM + d)*48 + m];
    }
    for (int jj = t; jj < 384; jj += 256)
        mbl[jj] = (INF_F*LOG2E_F) * (mask[(size_t)ii*I_DIM + jj] - 1.f);
    __syncthreads();

    const int w = t >> 6, l = t & 63;
    const int n16 = l & 15, quad = l >> 4;
    const int slA = n16 + ((quad & 1) << 5);   // source lane: quad' = 2*(quad&1)
    const int slB = slA + 16;                  // quad' + 1
    const bool hi = (quad & 2) != 0;           // selects k6 = 2km+1

    #pragma unroll 1
    for (int qt = 0; qt < 6; qt++) {
        const int qg = w*6 + qt;               // q rows qg*16..+15

        // ---- Q-frag (B-operand): bf16 row-major, single 16B load ----
        U4S8 a;
        a.u = *(const uint4*)(q16 + rbase + (size_t)(qg*16 + n16)*C_DIM + quad*8);

        f32x4 oacc0 = {0.f,0.f,0.f,0.f}, oacc1 = {0.f,0.f,0.f,0.f};
        float lsum = 0.f;
        const float* zrow = zb + (size_t)h*M_DIM
                          + (size_t)(qg*16 + n16)*I_DIM + quad*4;

        #pragma unroll 2
        for (int c = 0; c < 4; c++) {
            // C-init = z + mask bias (rides the MFMA C-operand for free)
            f32x4 cin[6];
            #pragma unroll
            for (int k6 = 0; k6 < 6; k6++) {
                const float4 z4 = *(const float4*)&zrow[96*c + k6*16];
                const float4 m4 = *(const float4*)&mbl[96*c + k6*16 + quad*4];
                cin[k6][0] = z4.x + m4.x;
                cin[k6][1] = z4.y + m4.y;
                cin[k6][2] = z4.z + m4.z;
                cin[k6][3] = z4.w + m4.w;
            }

            // ---- QK^T swapped, biased: accS = K·Q + (z+mask) ----
            f32x4 accS[6];
            __builtin_amdgcn_s_setprio(1);
            #pragma unroll
            for (int k6 = 0; k6 < 6; k6++) {
                const int key = (6*c + k6)*16 + n16;
                U4S8 b;
                b.u = Ks4[key*4 + (quad ^ ((key >> 1) & 3))];
                accS[k6] = __builtin_amdgcn_mfma_f32_16x16x32_bf16(
                    b.s, a.s, cin[k6], 0, 0, 0);
            }
            __builtin_amdgcn_s_setprio(0);

            // ---- exp2 + lane-local sum + pack to bf16 pairs ----
            unsigned int pu[6][2];
            #pragma unroll
            for (int k6 = 0; k6 < 6; k6++) {
                const float e0 = __builtin_amdgcn_exp2f(accS[k6][0]);
                const float e1 = __builtin_amdgcn_exp2f(accS[k6][1]);
                const float e2 = __builtin_amdgcn_exp2f(accS[k6][2]);
                const float e3 = __builtin_amdgcn_exp2f(accS[k6][3]);
                lsum += (e0 + e1) + (e2 + e3);
                pu[k6][0] = cvtpk(e0, e1);
                pu[k6][1] = cvtpk(e2, e3);
            }

            // ---- exchange (fixed quad permutation) + PV ----
            #pragma unroll
            for (int km = 0; km < 3; km++) {
                const unsigned int x0 = __shfl((int)pu[2*km  ][0], slA);
                const unsigned int x1 = __shfl((int)pu[2*km+1][0], slA);
                const unsigned int y0 = __shfl((int)pu[2*km  ][1], slA);
                const unsigned int y1 = __shfl((int)pu[2*km+1][1], slA);
                const unsigned int z0 = __shfl((int)pu[2*km  ][0], slB);
                const unsigned int z1 = __shfl((int)pu[2*km+1][0], slB);
                const unsigned int w0 = __shfl((int)pu[2*km  ][1], slB);
                const unsigned int w1 = __shfl((int)pu[2*km+1][1], slB);
                U4S8 pa;
                pa.u = make_uint4(hi?x1:x0, hi?y1:y0, hi?z1:z0, hi?w1:w0);
                U4S8 vb0, vb1;
                vb0.u = VTf[(c*6 + km*2    )*64 + l];
                vb1.u = VTf[(c*6 + km*2 + 1)*64 + l];
                __builtin_amdgcn_s_setprio(1);
                oacc0 = __builtin_amdgcn_mfma_f32_16x16x32_bf16(vb0.s, pa.s, oacc0, 0,0,0);
                oacc1 = __builtin_amdgcn_mfma_f32_16x16x32_bf16(vb1.s, pa.s, oacc1, 0,0,0);
                __builtin_amdgcn_s_setprio(0);
            }
        }

        // ---- normalize, fuse gate, store hi/lo pairs ----
        float s_ = lsum;
        s_ += __shfl_xor(s_, 16);
        s_ += __shfl_xor(s_, 32);
        const float rcp = 1.f / s_;
        const size_t orow = rbase + (size_t)(qg*16 + n16)*C_DIM;
        const float4 g0 = *(const float4*)&g[orow + quad*4];
        const float4 g1 = *(const float4*)&g[orow + 16 + quad*4];
        const float o00 = oacc0[0]*rcp, o01 = oacc0[1]*rcp,
                    o02 = oacc0[2]*rcp, o03 = oacc0[3]*rcp;
        const float o10 = oacc1[0]*rcp, o11 = oacc1[1]*rcp,
                    o12 = oacc1[2]*rcp, o13 = oacc1[3]*rcp;
        uint4 w0_, w1_;
        w0_.x = hl32(o00*g0.x); w0_.y = hl32(o01*g0.y);
        w0_.z = hl32(o02*g0.z); w0_.w = hl32(o03*g0.w);
        w1_.x = hl32(o10*g1.x); w1_.y = hl32(o11*g1.y);
        w1_.z = hl32(o12*g1.z); w1_.w = hl32(o13*g1.w);
        *(uint4*)&og[orow + quad*4]      = w0_;
        *(uint4*)&og[orow + 16 + quad*4] = w1_;
    }
}

// ---------------------------------------------------------------------------
// Kernel 3: out = p @ wo + bo where p = o*g arrives PRE-SPLIT as hi/lo bf16
// pairs (uint/elem) from attention. (round-10 verified version, unchanged.)
// ---------------------------------------------------------------------------
__global__ __launch_bounds__(256, 3) void out_proj_kernel(
    const unsigned int* __restrict__ og,
    const float* __restrict__ bo, float* out)
{
    __shared__ __align__(16) unsigned int xs[4096];
    __shared__ __align__(16) uint4 wbuf4[2048];       // 2 x 16KB dbuf
    const int t    = threadIdx.x;
    const int row0 = blockIdx.x * 64;
    const int w = t >> 6, l = t & 63, n16 = l & 15, quad = l >> 4;

    // prefetch wo quarter 0 -> buffer 0
    #pragma unroll
    for (int it = 0; it < 4; ++it) {
        const int tl = w*4 + it;
        const int s = tl >> 3, ntl = (tl >> 2) & 1, ks = tl & 3;
        load_lds16(wfmt_dev + (size_t)4*4096 + (size_t)((s*8 + ntl)*4 + ks)*64 + l,
                   (char*)wbuf4 + tl*1024);
    }

    uint4 pw[8];                       // 32 packed hi|lo elems
    const int r = t >> 2, qt = t & 3, c0 = qt * 32;
    const int sw = (r & 7) << 2;
    {
        const uint4* prow = (const uint4*)(og + (size_t)(row0 + r)*C_DIM + c0);
        #pragma unroll
        for (int i2 = 0; i2 < 8; i2++) {
            pw[i2] = prow[i2];
            const int wi = r*64 + qt*16 + i2*2;
            xs[(wi  ) ^ sw] = (pw[i2].x & 0xffffu) | (pw[i2].y << 16);
            xs[(wi+1) ^ sw] = (pw[i2].z & 0xffffu) | (pw[i2].w << 16);
        }
    }
    __syncthreads();

    U4S8 ah[4], al[4];
    const int arow = w*16 + n16;
    #pragma unroll
    for (int ks = 0; ks < 4; ++ks) {
        const int bofs = arow*256 + ((ks*64 + quad*16) ^ ((arow & 7) << 4));
        ah[ks].u = *(const uint4*)((const char*)xs + bofs);
    }
    __syncthreads();
    #pragma unroll
    for (int i2 = 0; i2 < 8; i2++) {
        const int wi = r*64 + qt*16 + i2*2;
        xs[(wi  ) ^ sw] = (pw[i2].x >> 16) | (pw[i2].y & 0xffff0000u);
        xs[(wi+1) ^ sw] = (pw[i2].z >> 16) | (pw[i2].w & 0xffff0000u);
    }
    __syncthreads();
    #pragma unroll
    for (int ks = 0; ks < 4; ++ks) {
        const int bofs = arow*256 + ((ks*64 + quad*16) ^ ((arow & 7) << 4));
        al[ks].u = *(const uint4*)((const char*)xs + bofs);
    }

    const int rw0 = row0 + w*16 + quad*4;
    int p = 0;
    #pragma unroll
    for (int qq = 0; qq < 4; ++qq) {
        if (qq < 3) {
            const int q2 = qq + 1;
            #pragma unroll
            for (int it = 0; it < 4; ++it) {
                const int tl = w*4 + it;
                const int s = tl >> 3, ntl2 = (tl >> 2) & 1, ks = tl & 3;
                load_lds16(wfmt_dev + (size_t)4*4096
                           + (size_t)((s*8 + (q2*2 + ntl2))*4 + ks)*64 + l,
                           (char*)wbuf4 + (p^1)*16384 + tl*1024);
            }
        }
        f32x4 acc[2];
        #pragma unroll
        for (int ntl = 0; ntl < 2; ++ntl) {
            f32x4 a = {0.f, 0.f, 0.f, 0.f};
            #pragma unroll
            for (int ks = 0; ks < 4; ++ks) {
                U4S8 bh, bl;
                bh.u = wbuf4[p*1024 + (    ntl*4 + ks)*64 + l];
                bl.u = wbuf4[p*1024 + (8 + ntl*4 + ks)*64 + l];
                a = __builtin_amdgcn_mfma_f32_16x16x32_bf16(ah[ks].s, bh.s, a, 0,0,0);
                a = __builtin_amdgcn_mfma_f32_16x16x32_bf16(al[ks].s, bh.s, a, 0,0,0);
                a = __builtin_amdgcn_mfma_f32_16x16x32_bf16(ah[ks].s, bl.s, a, 0,0,0);
            }
            acc[ntl] = a;
        }
        #pragma unroll
        for (int ntl = 0; ntl < 2; ++ntl) {
            const int n = qq*32 + ntl*16 + n16;
            const float bov = bo[n];
            #pragma unroll
            for (int rr = 0; rr < 4; ++rr)
                out[(size_t)(rw0 + rr)*C_DIM + n] = acc[ntl][rr] + bov;
        }
        __syncthreads();
        p ^= 1;
    }
}

extern "C" void kernel_launch(void* const* d_in, const int* in_sizes, int n_in,
                              void* d_out, int out_size, void* d_ws, size_t ws_size,
                              hipStream_t stream)
{
    (void)in_sizes; (void)n_in; (void)out_size; (void)ws_size;
    const float* x    = (const float*)d_in[0];
    const float* mask = (const float*)d_in[1];
    const float* lnw  = (const float*)d_in[2];
    const float* lnb  = (const float*)d_in[3];
    const float* wz   = (const float*)d_in[4];
    const float* bz   = (const float*)d_in[5];
    const float* wq   = (const float*)d_in[6];
    const float* wk   = (const float*)d_in[7];
    const float* wv   = (const float*)d_in[8];
    const float* wg   = (const float*)d_in[9];
    const float* bg   = (const float*)d_in[10];
    const float* wo   = (const float*)d_in[11];
    const float* bo   = (const float*)d_in[12];

    // ws layout (offsets unchanged; q region holds bf16, o*g lives in d_out):
    //   qb   region M*128 fp32-sized; q bf16 uses first half
    //   zbuf fp32 4*M    (pre-scaled by LOG2E)
    //   kb16 bf16 M*128 row-major
    //   vt32 bf16 M*128 transposed [i][c][j], packed uint pairs along j
    float* ws = (float*)d_ws;
    float* qb   = ws;
    float* zbuf = qb + (size_t)M_DIM*C_DIM;
    unsigned short* kb16 = (unsigned short*)(zbuf + (size_t)H_NUM*M_DIM);
    unsigned int*   vt32 = (unsigned int*)(kb16 + (size_t)M_DIM*C_DIM);
    unsigned short* q16  = (unsigned short*)qb;
    float* gbuf = (float*)d_out;     // g parked in d_out; attn replaces it
                                     // in-place with packed (o*g) hi/lo pairs

    wprep_kernel<<<80, 256, 0, stream>>>(wq, wk, wg, wv, wo);
    ln_proj_kernel<<<M_DIM/64, 256, 0, stream>>>(
        x, lnw, lnb, wz, bz, bg, q16, kb16, vt32, gbuf, zbuf);
    attn_mfma_kernel<<<dim3(I_DIM, H_NUM), 256, 0, stream>>>(
        q16, kb16, vt32, zbuf, mask, gbuf, (unsigned int*)d_out);
    out_proj_kernel<<<M_DIM/64, 256, 0, stream>>>(
        (const unsigned int*)d_out, bo, (float*)d_out);
}